// Round 2
// baseline (339.144 us; speedup 1.0000x reference)
//
#include <hip/hip_runtime.h>

#define NS 5      // symbols
#define NW 33     // subcarriers
#define NA 16     // antennas (4x4)
#define SW 165    // NS*NW
#define G 4       // matrices per block
#define THREADS 256

__global__ __launch_bounds__(THREADS) void autocorr_kernel(
    const float* __restrict__ x_real, const float* __restrict__ x_imag,
    const float* __restrict__ Fsym_re, const float* __restrict__ Fsym_im,
    const float* __restrict__ Fsub_re, const float* __restrict__ Fsub_im,
    float* __restrict__ out, int NM, int write_complex)
{
    __shared__ float2 sFsym[NS * NS];     // [s][t]
    __shared__ float2 sFsub[NW * NW];     // [w][v]
    __shared__ float2 sFsubT[NW * NW];    // [v][q] = Fsub[q][v]
    __shared__ float2 xs[G][SW];          // input x; reused for T2
    __shared__ float2 t1[G][SW];          // T1
    __shared__ float  ps[G][SW];          // P = |X|^2 (real)

    const int tid = threadIdx.x;
    const int M0 = blockIdx.x * G;

    // Stage F matrices into LDS (both layouts of Fsub)
    for (int i = tid; i < NW * NW; i += THREADS) {
        int w = i / NW, v = i % NW;
        float2 f = make_float2(Fsub_re[i], Fsub_im[i]);
        sFsub[i] = f;
        sFsubT[v * NW + w] = f;
    }
    if (tid < NS * NS) sFsym[tid] = make_float2(Fsym_re[tid], Fsym_im[tid]);

    // Load G matrices of x into LDS
    for (int e = tid; e < G * SW; e += THREADS) {
        int g = e / SW, r = e % SW;
        int t = r / NW, w = r % NW;
        int M = M0 + g;
        if (M < NM) {
            int n = M >> 4, a = M & 15;
            int off = ((n * NS + t) * NA + a) * NW + w;
            xs[g][r] = make_float2(x_real[off], x_imag[off]);
        } else {
            xs[g][r] = make_float2(0.f, 0.f);
        }
    }
    __syncthreads();

    // Stage A: T1[s][w] = sum_t Fsym[s][t] * x[t][w]
    for (int e = tid; e < G * SW; e += THREADS) {
        int g = e / SW, r = e % SW;
        int s = r / NW, w = r % NW;
        float acr = 0.f, aci = 0.f;
#pragma unroll
        for (int t = 0; t < NS; ++t) {
            float2 f = sFsym[s * NS + t];
            float2 xv = xs[g][t * NW + w];
            acr = fmaf(f.x, xv.x, acr);
            acr = fmaf(-f.y, xv.y, acr);
            aci = fmaf(f.x, xv.y, aci);
            aci = fmaf(f.y, xv.x, aci);
        }
        t1[g][r] = make_float2(acr, aci);
    }
    __syncthreads();

    // Stage B: X[s][v] = sum_w T1[s][w] * Fsub[w][v];  P = |X|^2
    for (int e = tid; e < G * SW; e += THREADS) {
        int g = e / SW, r = e % SW;
        int s = r / NW, v = r % NW;
        float acr = 0.f, aci = 0.f;
#pragma unroll
        for (int w = 0; w < NW; ++w) {
            float2 tv = t1[g][s * NW + w];   // broadcast within row
            float2 f = sFsub[w * NW + v];    // contiguous across lanes
            acr = fmaf(tv.x, f.x, acr);
            acr = fmaf(-tv.y, f.y, acr);
            aci = fmaf(tv.x, f.y, aci);
            aci = fmaf(tv.y, f.x, aci);
        }
        ps[g][r] = acr * acr + aci * aci;
    }
    __syncthreads();

    // Stage D: T2[p][v] = sum_s conj(Fsym[s][p]) * P[s][v]   (P real)
    for (int e = tid; e < G * SW; e += THREADS) {
        int g = e / SW, r = e % SW;
        int p = r / NW, v = r % NW;
        float acr = 0.f, aci = 0.f;
#pragma unroll
        for (int s = 0; s < NS; ++s) {
            float2 f = sFsym[s * NS + p];
            float pv = ps[g][s * NW + v];
            acr = fmaf(f.x, pv, acr);
            aci = fmaf(-f.y, pv, aci);
        }
        xs[g][r] = make_float2(acr, aci);   // reuse xs for T2
    }
    __syncthreads();

    // Stage E: Y[p][q] = sum_v T2[p][v] * conj(Fsub[q][v])
    for (int e = tid; e < G * SW; e += THREADS) {
        int g = e / SW, r = e % SW;
        int p = r / NW, q = r % NW;
        float acr = 0.f, aci = 0.f;
#pragma unroll
        for (int v = 0; v < NW; ++v) {
            float2 tv = xs[g][p * NW + v];    // broadcast within row
            float2 f = sFsubT[v * NW + q];    // contiguous across lanes
            // tv * conj(f)
            acr = fmaf(tv.x, f.x, acr);
            acr = fmaf(tv.y, f.y, acr);
            aci = fmaf(tv.y, f.x, aci);
            aci = fmaf(-tv.x, f.y, aci);
        }
        int M = M0 + g;
        if (M < NM) {
            int n = M >> 4, a = M & 15;
            long long idx = ((long long)(n * NS + p) * NA + a) * NW + q;
            if (write_complex) {
                // d_out is complex64 flattened as float pairs
                ((float2*)out)[idx] = make_float2(acr, aci);
            } else {
                // d_out holds out_size float32 elements (real part only)
                out[idx] = acr;
            }
        }
    }
}

extern "C" void kernel_launch(void* const* d_in, const int* in_sizes, int n_in,
                              void* d_out, int out_size, void* d_ws, size_t ws_size,
                              hipStream_t stream) {
    const float* x_real  = (const float*)d_in[0];
    const float* x_imag  = (const float*)d_in[1];
    const float* Fsym_re = (const float*)d_in[2];
    const float* Fsym_im = (const float*)d_in[3];
    const float* Fsub_re = (const float*)d_in[4];
    const float* Fsub_im = (const float*)d_in[5];

    const int NM = in_sizes[0] / SW;               // N * 16 matrices
    const long long n_cplx = (long long)in_sizes[0];  // logical complex outputs
    // If the harness flattened complex64 as float pairs, out_size == 2*n_cplx.
    const int write_complex = ((long long)out_size >= 2 * n_cplx) ? 1 : 0;

    const int blocks = (NM + G - 1) / G;

    autocorr_kernel<<<blocks, THREADS, 0, stream>>>(
        x_real, x_imag, Fsym_re, Fsym_im, Fsub_re, Fsub_im,
        (float*)d_out, NM, write_complex);
}

// Round 3
// 210.687 us; speedup vs baseline: 1.6097x; 1.6097x over previous
//
#include <hip/hip_runtime.h>

#define NS 5      // symbols
#define NW 33     // subcarriers
#define NA 16     // antennas
#define SW 165    // NS*NW
#define GM 23     // matrices per block
#define TPM 11    // threads per matrix (33 cols / 3 per thread)
#define CPT 3     // columns per thread
#define THREADS 256
#define ACTIVE (GM*TPM)   // 253

__global__ __launch_bounds__(THREADS, 2) void autocorr_kernel(
    const float* __restrict__ x_real, const float* __restrict__ x_imag,
    const float* __restrict__ Fsym_re, const float* __restrict__ Fsym_im,
    const float* __restrict__ Fsub_re, const float* __restrict__ Fsub_im,
    float* __restrict__ out, int NM, int write_complex)
{
    __shared__ float2 sFsym[NS * NS];     // [s][t]
    __shared__ float2 sFsub[NW * NW];     // [w][v] row-major
    __shared__ float2 sFsubT[NW * NW];    // [v][q] = Fsub[q][v]
    __shared__ float2 buf[GM][SW];        // x (row-major [t][w]) -> T1 (col-major [w][s]) -> T2 (col-major [v][p])

    const int tid = threadIdx.x;
    const int M0 = blockIdx.x * GM;

    // ---- Stage F matrices into LDS ----
    for (int i = tid; i < NW * NW; i += THREADS) {
        int w = i / NW, v = i % NW;
        float2 f = make_float2(Fsub_re[i], Fsub_im[i]);
        sFsub[i] = f;
        sFsubT[v * NW + w] = f;
    }
    if (tid < NS * NS) sFsym[tid] = make_float2(Fsym_re[tid], Fsym_im[tid]);

    // ---- Stage x into LDS (coalesced) ----
    for (int e = tid; e < GM * SW; e += THREADS) {
        int g = e / SW, r = e % SW;
        int M = M0 + g;
        if (M < NM) {
            int t = r / NW, w = r % NW;
            int n = M >> 4, a = M & 15;
            int off = ((n * NS + t) * NA + a) * NW + w;
            buf[g][r] = make_float2(x_real[off], x_imag[off]);
        } else {
            buf[g][r] = make_float2(0.f, 0.f);
        }
    }
    __syncthreads();

    const int g = tid / TPM;
    const int j = tid - g * TPM;
    const bool act = (tid < ACTIVE);
    const int M = M0 + g;
    const int c0 = 3 * j;   // first owned column

    // ---- read my x columns into registers ----
    float2 xr[NS][CPT];
    if (act) {
#pragma unroll
        for (int t = 0; t < NS; ++t)
#pragma unroll
            for (int k = 0; k < CPT; ++k)
                xr[t][k] = buf[g][t * NW + c0 + k];
    }
    __syncthreads();   // everyone done reading x before T1 overwrites buf

    // ---- Stage A: T1[s][w] = sum_t Fsym[s][t] * x[t][w] (thread-local) ----
    float2 A[NS][CPT];
    if (act) {
#pragma unroll
        for (int s = 0; s < NS; ++s)
#pragma unroll
            for (int k = 0; k < CPT; ++k) A[s][k] = make_float2(0.f, 0.f);
#pragma unroll
        for (int t = 0; t < NS; ++t) {
#pragma unroll
            for (int s = 0; s < NS; ++s) {
                float2 f = sFsym[s * NS + t];   // all-lane broadcast
#pragma unroll
                for (int k = 0; k < CPT; ++k) {
                    A[s][k].x = fmaf(f.x, xr[t][k].x, A[s][k].x);
                    A[s][k].x = fmaf(-f.y, xr[t][k].y, A[s][k].x);
                    A[s][k].y = fmaf(f.x, xr[t][k].y, A[s][k].y);
                    A[s][k].y = fmaf(f.y, xr[t][k].x, A[s][k].y);
                }
            }
        }
        // write T1 column-major: buf[g][w*NS + s], w = c0+k  (contiguous 15 float2/thread)
#pragma unroll
        for (int k = 0; k < CPT; ++k)
#pragma unroll
            for (int s = 0; s < NS; ++s)
                buf[g][(c0 + k) * NS + s] = A[s][k];
    }
    __syncthreads();

    // ---- Stage B: X[s][v] = sum_w T1[s][w] * Fsub[w][v];  P = |X|^2 ----
    float2 X[NS][CPT];
#pragma unroll
    for (int s = 0; s < NS; ++s)
#pragma unroll
        for (int k = 0; k < CPT; ++k) X[s][k] = make_float2(0.f, 0.f);
    if (act) {
        for (int w = 0; w < NW; ++w) {
            float2 tc[NS];
#pragma unroll
            for (int s = 0; s < NS; ++s) tc[s] = buf[g][w * NS + s];   // broadcast within matrix
            float2 fv[CPT];
#pragma unroll
            for (int k = 0; k < CPT; ++k) fv[k] = sFsub[w * NW + c0 + k]; // dedup across matrices
#pragma unroll
            for (int s = 0; s < NS; ++s)
#pragma unroll
                for (int k = 0; k < CPT; ++k) {
                    X[s][k].x = fmaf(tc[s].x, fv[k].x, X[s][k].x);
                    X[s][k].x = fmaf(-tc[s].y, fv[k].y, X[s][k].x);
                    X[s][k].y = fmaf(tc[s].x, fv[k].y, X[s][k].y);
                    X[s][k].y = fmaf(tc[s].y, fv[k].x, X[s][k].y);
                }
        }
    }
    __syncthreads();   // all T1 reads done before T2 overwrites buf

    // ---- P = |X|^2 ; Stage D: T2[p][v] = sum_s conj(Fsym[s][p]) * P[s][v] (thread-local) ----
    if (act) {
        float P[NS][CPT];
#pragma unroll
        for (int s = 0; s < NS; ++s)
#pragma unroll
            for (int k = 0; k < CPT; ++k)
                P[s][k] = X[s][k].x * X[s][k].x + X[s][k].y * X[s][k].y;

        float2 T2[NS][CPT];   // [p][k]
#pragma unroll
        for (int p = 0; p < NS; ++p)
#pragma unroll
            for (int k = 0; k < CPT; ++k) T2[p][k] = make_float2(0.f, 0.f);
#pragma unroll
        for (int s = 0; s < NS; ++s) {
#pragma unroll
            for (int p = 0; p < NS; ++p) {
                float2 f = sFsym[s * NS + p];   // conj applied in MAC
#pragma unroll
                for (int k = 0; k < CPT; ++k) {
                    T2[p][k].x = fmaf(f.x, P[s][k], T2[p][k].x);
                    T2[p][k].y = fmaf(-f.y, P[s][k], T2[p][k].y);
                }
            }
        }
        // write T2 column-major: buf[g][v*NS + p], v = c0+k
#pragma unroll
        for (int k = 0; k < CPT; ++k)
#pragma unroll
            for (int p = 0; p < NS; ++p)
                buf[g][(c0 + k) * NS + p] = T2[p][k];
    }
    __syncthreads();

    // ---- Stage E: Y[p][q] = sum_v T2[p][v] * conj(Fsub[q][v]) ----
    if (act) {
        float2 Y[NS][CPT];
#pragma unroll
        for (int p = 0; p < NS; ++p)
#pragma unroll
            for (int k = 0; k < CPT; ++k) Y[p][k] = make_float2(0.f, 0.f);
        for (int v = 0; v < NW; ++v) {
            float2 tc[NS];
#pragma unroll
            for (int p = 0; p < NS; ++p) tc[p] = buf[g][v * NS + p];    // broadcast within matrix
            float2 fv[CPT];
#pragma unroll
            for (int k = 0; k < CPT; ++k) fv[k] = sFsubT[v * NW + c0 + k]; // = Fsub[q][v]
#pragma unroll
            for (int p = 0; p < NS; ++p)
#pragma unroll
                for (int k = 0; k < CPT; ++k) {
                    // tc * conj(fv)
                    Y[p][k].x = fmaf(tc[p].x, fv[k].x, Y[p][k].x);
                    Y[p][k].x = fmaf(tc[p].y, fv[k].y, Y[p][k].x);
                    Y[p][k].y = fmaf(tc[p].y, fv[k].x, Y[p][k].y);
                    Y[p][k].y = fmaf(-tc[p].x, fv[k].y, Y[p][k].y);
                }
        }
        if (M < NM) {
            int n = M >> 4, a = M & 15;
#pragma unroll
            for (int p = 0; p < NS; ++p)
#pragma unroll
                for (int k = 0; k < CPT; ++k) {
                    int idx = ((n * NS + p) * NA + a) * NW + c0 + k;
                    if (write_complex) {
                        ((float2*)out)[idx] = Y[p][k];
                    } else {
                        out[idx] = Y[p][k].x;
                    }
                }
        }
    }
}

extern "C" void kernel_launch(void* const* d_in, const int* in_sizes, int n_in,
                              void* d_out, int out_size, void* d_ws, size_t ws_size,
                              hipStream_t stream) {
    const float* x_real  = (const float*)d_in[0];
    const float* x_imag  = (const float*)d_in[1];
    const float* Fsym_re = (const float*)d_in[2];
    const float* Fsym_im = (const float*)d_in[3];
    const float* Fsub_re = (const float*)d_in[4];
    const float* Fsub_im = (const float*)d_in[5];

    const int NM = in_sizes[0] / SW;                  // N*16 matrices
    const long long n_cplx = (long long)in_sizes[0];
    const int write_complex = ((long long)out_size >= 2 * n_cplx) ? 1 : 0;

    const int blocks = (NM + GM - 1) / GM;

    autocorr_kernel<<<blocks, THREADS, 0, stream>>>(
        x_real, x_imag, Fsym_re, Fsym_im, Fsub_re, Fsub_im,
        (float*)d_out, NM, write_complex);
}

// Round 4
// 201.419 us; speedup vs baseline: 1.6838x; 1.0460x over previous
//
#include <hip/hip_runtime.h>

#define NS 5      // symbols
#define NW 33     // subcarriers
#define NA 16     // antennas
#define SW 165    // NS*NW
#define GM 23     // matrices per block
#define TPM 11    // threads per matrix (33 cols / 3 per thread)
#define CPT 3     // columns per thread
#define THREADS 256
#define ACTIVE (GM*TPM)   // 253

__global__ __launch_bounds__(THREADS, 4) void autocorr_kernel(
    const float* __restrict__ x_real, const float* __restrict__ x_imag,
    const float* __restrict__ Fsym_re, const float* __restrict__ Fsym_im,
    const float* __restrict__ Fsub_re, const float* __restrict__ Fsub_im,
    float* __restrict__ out, int NM, int write_complex)
{
    __shared__ float2 sFsym[NS * NS];     // [s][t]
    __shared__ float2 sFsub[NW * NW];     // [w][v] row-major (serves both B and E)
    __shared__ float2 buf[GM][SW];        // x (row-major [t][w]) -> T1 (col-major [w][s]) -> T2 (col-major [v][p])

    const int tid = threadIdx.x;
    const int M0 = blockIdx.x * GM;

    // ---- Stage F matrices into LDS ----
    for (int i = tid; i < NW * NW; i += THREADS) {
        sFsub[i] = make_float2(Fsub_re[i], Fsub_im[i]);
    }
    if (tid < NS * NS) sFsym[tid] = make_float2(Fsym_re[tid], Fsym_im[tid]);

    // ---- Stage x into LDS (coalesced) ----
    for (int e = tid; e < GM * SW; e += THREADS) {
        int g = e / SW, r = e % SW;
        int M = M0 + g;
        if (M < NM) {
            int t = r / NW, w = r % NW;
            int n = M >> 4, a = M & 15;
            int off = ((n * NS + t) * NA + a) * NW + w;
            buf[g][r] = make_float2(x_real[off], x_imag[off]);
        } else {
            buf[g][r] = make_float2(0.f, 0.f);
        }
    }
    __syncthreads();

    const int g = tid / TPM;
    const int j = tid - g * TPM;
    const bool act = (tid < ACTIVE);
    const int M = M0 + g;
    const int c0 = 3 * j;   // first owned column

    // ---- read my x columns into registers ----
    float2 xr[NS][CPT];
    if (act) {
#pragma unroll
        for (int t = 0; t < NS; ++t)
#pragma unroll
            for (int k = 0; k < CPT; ++k)
                xr[t][k] = buf[g][t * NW + c0 + k];
    }
    __syncthreads();   // everyone done reading x before T1 overwrites buf

    // ---- Stage A: T1[s][w] = sum_t Fsym[s][t] * x[t][w] (thread-local) ----
    if (act) {
        float2 A[NS][CPT];
#pragma unroll
        for (int s = 0; s < NS; ++s)
#pragma unroll
            for (int k = 0; k < CPT; ++k) A[s][k] = make_float2(0.f, 0.f);
#pragma unroll
        for (int t = 0; t < NS; ++t) {
#pragma unroll
            for (int s = 0; s < NS; ++s) {
                float2 f = sFsym[s * NS + t];   // all-lane broadcast
#pragma unroll
                for (int k = 0; k < CPT; ++k) {
                    A[s][k].x = fmaf(f.x, xr[t][k].x, A[s][k].x);
                    A[s][k].x = fmaf(-f.y, xr[t][k].y, A[s][k].x);
                    A[s][k].y = fmaf(f.x, xr[t][k].y, A[s][k].y);
                    A[s][k].y = fmaf(f.y, xr[t][k].x, A[s][k].y);
                }
            }
        }
        // write T1 column-major: buf[g][w*NS + s], w = c0+k
#pragma unroll
        for (int k = 0; k < CPT; ++k)
#pragma unroll
            for (int s = 0; s < NS; ++s)
                buf[g][(c0 + k) * NS + s] = A[s][k];
    }
    __syncthreads();

    // ---- Stage B: X[s][v] = sum_w T1[s][w] * Fsub[w][v];  P = |X|^2 ----
    float2 X[NS][CPT];
#pragma unroll
    for (int s = 0; s < NS; ++s)
#pragma unroll
        for (int k = 0; k < CPT; ++k) X[s][k] = make_float2(0.f, 0.f);
    if (act) {
#pragma unroll 3
        for (int w = 0; w < NW; ++w) {
            float2 tc[NS];
#pragma unroll
            for (int s = 0; s < NS; ++s) tc[s] = buf[g][w * NS + s];   // broadcast within matrix
            float2 fv[CPT];
#pragma unroll
            for (int k = 0; k < CPT; ++k) fv[k] = sFsub[w * NW + c0 + k]; // distinct banks per j
#pragma unroll
            for (int s = 0; s < NS; ++s)
#pragma unroll
                for (int k = 0; k < CPT; ++k) {
                    X[s][k].x = fmaf(tc[s].x, fv[k].x, X[s][k].x);
                    X[s][k].x = fmaf(-tc[s].y, fv[k].y, X[s][k].x);
                    X[s][k].y = fmaf(tc[s].x, fv[k].y, X[s][k].y);
                    X[s][k].y = fmaf(tc[s].y, fv[k].x, X[s][k].y);
                }
        }
    }
    __syncthreads();   // all T1 reads done before T2 overwrites buf

    // ---- P = |X|^2 ; Stage D: T2[p][v] = sum_s conj(Fsym[s][p]) * P[s][v] (thread-local) ----
    if (act) {
        float P[NS][CPT];
#pragma unroll
        for (int s = 0; s < NS; ++s)
#pragma unroll
            for (int k = 0; k < CPT; ++k)
                P[s][k] = X[s][k].x * X[s][k].x + X[s][k].y * X[s][k].y;

        float2 T2[NS][CPT];   // [p][k]
#pragma unroll
        for (int p = 0; p < NS; ++p)
#pragma unroll
            for (int k = 0; k < CPT; ++k) T2[p][k] = make_float2(0.f, 0.f);
#pragma unroll
        for (int s = 0; s < NS; ++s) {
#pragma unroll
            for (int p = 0; p < NS; ++p) {
                float2 f = sFsym[s * NS + p];   // conj applied in MAC
#pragma unroll
                for (int k = 0; k < CPT; ++k) {
                    T2[p][k].x = fmaf(f.x, P[s][k], T2[p][k].x);
                    T2[p][k].y = fmaf(-f.y, P[s][k], T2[p][k].y);
                }
            }
        }
        // write T2 column-major: buf[g][v*NS + p], v = c0+k
#pragma unroll
        for (int k = 0; k < CPT; ++k)
#pragma unroll
            for (int p = 0; p < NS; ++p)
                buf[g][(c0 + k) * NS + p] = T2[p][k];
    }
    __syncthreads();

    // ---- Stage E: Y[p][q] = sum_v T2[p][v] * conj(Fsub[q][v]),  q = c0+k ----
    if (act) {
        float2 Y[NS][CPT];
#pragma unroll
        for (int p = 0; p < NS; ++p)
#pragma unroll
            for (int k = 0; k < CPT; ++k) Y[p][k] = make_float2(0.f, 0.f);
#pragma unroll 3
        for (int v = 0; v < NW; ++v) {
            float2 tc[NS];
#pragma unroll
            for (int p = 0; p < NS; ++p) tc[p] = buf[g][v * NS + p];    // broadcast within matrix
            float2 fv[CPT];
#pragma unroll
            for (int k = 0; k < CPT; ++k) fv[k] = sFsub[(c0 + k) * NW + v]; // row (c0+k), col v
#pragma unroll
            for (int p = 0; p < NS; ++p)
#pragma unroll
                for (int k = 0; k < CPT; ++k) {
                    // tc * conj(fv)
                    Y[p][k].x = fmaf(tc[p].x, fv[k].x, Y[p][k].x);
                    Y[p][k].x = fmaf(tc[p].y, fv[k].y, Y[p][k].x);
                    Y[p][k].y = fmaf(tc[p].y, fv[k].x, Y[p][k].y);
                    Y[p][k].y = fmaf(-tc[p].x, fv[k].y, Y[p][k].y);
                }
        }
        if (M < NM) {
            int n = M >> 4, a = M & 15;
#pragma unroll
            for (int p = 0; p < NS; ++p)
#pragma unroll
                for (int k = 0; k < CPT; ++k) {
                    int idx = ((n * NS + p) * NA + a) * NW + c0 + k;
                    if (write_complex) {
                        ((float2*)out)[idx] = Y[p][k];
                    } else {
                        out[idx] = Y[p][k].x;
                    }
                }
        }
    }
}

extern "C" void kernel_launch(void* const* d_in, const int* in_sizes, int n_in,
                              void* d_out, int out_size, void* d_ws, size_t ws_size,
                              hipStream_t stream) {
    const float* x_real  = (const float*)d_in[0];
    const float* x_imag  = (const float*)d_in[1];
    const float* Fsym_re = (const float*)d_in[2];
    const float* Fsym_im = (const float*)d_in[3];
    const float* Fsub_re = (const float*)d_in[4];
    const float* Fsub_im = (const float*)d_in[5];

    const int NM = in_sizes[0] / SW;                  // N*16 matrices
    const long long n_cplx = (long long)in_sizes[0];
    const int write_complex = ((long long)out_size >= 2 * n_cplx) ? 1 : 0;

    const int blocks = (NM + GM - 1) / GM;

    autocorr_kernel<<<blocks, THREADS, 0, stream>>>(
        x_real, x_imag, Fsym_re, Fsym_im, Fsub_re, Fsub_im,
        (float*)d_out, NM, write_complex);
}